// Round 1
// 101.263 us; speedup vs baseline: 1.0115x; 1.0115x over previous
//
#include <hip/hip_runtime.h>
#include <hip/hip_bf16.h>

#define NH 8
#define HID 64
#define NPAIRS (16 * 256 * 256)
#define BLOCK 256
#define LROW 72          // bf16 per LDS row (64 + 8 pad) = 144 B, 16B-aligned

typedef __attribute__((ext_vector_type(8))) short bf16x8;
typedef __attribute__((ext_vector_type(4))) float f32x4;
typedef __attribute__((ext_vector_type(16))) float f32x16;

union F8 { bf16x8 v; unsigned u[4]; uint4 q4; };

// f32 pair -> packed bf16 dword (RNE, a in low half) via HW v_cvt_pk_bf16_f32
__device__ inline unsigned pk2(float a, float b) {
    __hip_bfloat162 h = __float22bfloat162_rn(make_float2(a, b));
    unsigned u;
    __builtin_memcpy(&u, &h, 4);
    return u;
}

__device__ inline float silu(float x) {
    return x * __builtin_amdgcn_rcpf(1.f + __expf(-x));
}

// Single kernel: weights are packed per-wave in registers (no pack_weights
// launch, no workspace). GEMM1 is operand-SWAPPED vs the previous version:
//   D1[hid][pair] = mfma(A = W1-frag, B = feat-frag)
// The 32x32x16 A and B lane layouts are symmetric (lane -> (l&31, k=8*(l>>5)+j)),
// so both the packed W1 fragment and the feature fragment are reused unchanged
// from the HW-verified previous kernel -- only the call's operand order and the
// D interpretation change. Benefit: each lane now holds 4 runs of 4 consecutive
// hid values for ONE pair -> silu results store as ds_write_b64 (4x fewer LDS
// ops) and cvt_pk count halves.
__global__ __launch_bounds__(BLOCK, 4) void relfeat_mfma4(
    const float* __restrict__ ff,
    const float* __restrict__ W1, const float* __restrict__ b1,
    const float* __restrict__ W2, const float* __restrict__ b2,
    float* __restrict__ out)
{
    __shared__ unsigned short lds[4][32 * LROW];   // 18432 B/block
    const int tid = threadIdx.x;
    const int w = tid >> 6, l = tid & 63;
    const int n32 = l & 31, q2 = l >> 5;
    const int n16 = l & 15, q4 = l >> 4;
    unsigned short* my = lds[w];                   // per-wave private, no barriers

    const int wave_base = (blockIdx.x * 4 + w) * 128;

    // Issue the ff loads first so HBM latency overlaps the weight build.
    float4 va = ((const float4*)ff)[wave_base + l];
    float4 vb = ((const float4*)ff)[wave_base + 64 + l];

    // ---- build weight fragments in-register (scalar loads, L1/L2-cached) ----
    // B1f[m]: 32x32x16 layout, lane holds W1[k = q2*8 + j][hid = m*32 + n32];
    //         k row 12 carries b1 (bias-as-feature, pairs with constant 1.0).
    F8 B1f[2], B2f[2];
    #pragma unroll
    for (int m = 0; m < 2; ++m) {
        int h = m * 32 + n32;
        #pragma unroll
        for (int j2 = 0; j2 < 4; ++j2) {
            int k0 = q2 * 8 + 2 * j2, k1 = k0 + 1;
            float v0 = (k0 < 12) ? W1[k0 * HID + h] : (k0 == 12 ? b1[h] : 0.f);
            float v1 = (k1 < 12) ? W1[k1 * HID + h] : 0.f;
            B1f[m].u[j2] = pk2(v0, v1);
        }
    }
    // B2f[kc]: 16x16x32 B-layout, lane holds W2[k = kc*32 + q4*8 + j][n16]
    #pragma unroll
    for (int kc = 0; kc < 2; ++kc) {
        #pragma unroll
        for (int j2 = 0; j2 < 4; ++j2) {
            int k0 = kc * 32 + q4 * 8 + 2 * j2;
            float v0 = (n16 < NH) ? W2[k0 * NH + n16] : 0.f;
            float v1 = (n16 < NH) ? W2[(k0 + 1) * NH + n16] : 0.f;
            B2f[kc].u[j2] = pk2(v0, v1);
        }
    }
    const float b2s = (n16 < NH) ? b2[n16] : 0.f;

    f32x16 z16;
    #pragma unroll
    for (int r = 0; r < 16; ++r) z16[r] = 0.f;

    #pragma unroll
    for (int it = 0; it < 2; ++it) {
        const int pbase = wave_base + it * 64;
        float4 v = it ? vb : va;

        // ---- each lane computes ITS OWN pair (pbase + l) features ----
        float rx = v.x, ry = v.y, rvx = v.z, rvy = v.w;
        float dist = sqrtf(rx * rx + ry * ry + 1e-6f);
        float speed_sq = rvx * rvx + rvy * rvy;
        float dot_vp = rvx * rx + rvy * ry;
        float invd = __builtin_amdgcn_rcpf(dist + 1e-6f);
        float inv_dist = __builtin_amdgcn_rcpf(dist + 0.1f);
        float rel_speed = sqrtf(speed_sq + 1e-6f);
        float closing = dot_vp * invd;
        float dir_x = rx * invd, dir_y = ry * invd;
        float zz = -dot_vp * __builtin_amdgcn_rcpf(speed_sq + 1e-6f);
        float ez = __expf(2.f * zz);
        float ttca = 1.f - 2.f * __builtin_amdgcn_rcpf(ez + 1.f);   // tanh(zz)

        unsigned c0 = pk2(rx, ry), c1 = pk2(rvx, rvy);
        unsigned c2 = pk2(dist, inv_dist), c3 = pk2(rel_speed, closing);
        unsigned c4 = pk2(dir_x, dir_y), c5 = pk2(ttca, dot_vp);
        // exchange halves: low lanes get high-lane data and vice versa
        unsigned sw0 = (unsigned)__shfl_xor((int)c0, 32);
        unsigned sw1 = (unsigned)__shfl_xor((int)c1, 32);
        unsigned sw2 = (unsigned)__shfl_xor((int)c2, 32);
        unsigned sw3 = (unsigned)__shfl_xor((int)c3, 32);
        unsigned sw4 = (unsigned)__shfl_xor((int)c4, 32);
        unsigned sw5 = (unsigned)__shfl_xor((int)c5, 32);

        // Feature fragment: B-layout B[k = q2*8 + j][pair = n32] for group G.
        // (identical data to the previously HW-verified A-layout fragment)
        const bool hi = (q2 != 0);
        F8 frag[2];
        frag[0].u[0] = hi ? sw4 : c0;            // k 8,9  | k 0,1
        frag[0].u[1] = hi ? sw5 : c1;            // k10,11 | k 2,3
        frag[0].u[2] = hi ? 0x00003f80u : c2;    // k12=1 (bias), 13=0 | k 4,5
        frag[0].u[3] = hi ? 0u : c3;             // k14,15=0 | k 6,7
        frag[1].u[0] = hi ? c4 : sw0;
        frag[1].u[1] = hi ? c5 : sw1;
        frag[1].u[2] = hi ? 0x00003f80u : sw2;
        frag[1].u[3] = hi ? 0u : sw3;

        #pragma unroll
        for (int G = 0; G < 2; ++G) {
            const int pg = pbase + G * 32;

            // GEMM1 (swapped): D1[hid][pair]; lane: pair = n32,
            // hid = mh*32 + (r&3) + 8*(r>>2) + 4*q2  ->  4 runs of 4 consec hid
            #pragma unroll
            for (int mh = 0; mh < 2; ++mh) {
                f32x16 d1 = __builtin_amdgcn_mfma_f32_32x32x16_bf16(
                                B1f[mh].v, frag[G].v, z16, 0, 0, 0);
                #pragma unroll
                for (int t = 0; t < 4; ++t) {
                    float s0 = silu(d1[4 * t + 0]);
                    float s1 = silu(d1[4 * t + 1]);
                    float s2 = silu(d1[4 * t + 2]);
                    float s3 = silu(d1[4 * t + 3]);
                    uint2 wv;
                    wv.x = pk2(s0, s1);
                    wv.y = pk2(s2, s3);
                    // LDS[pair = n32][hid = mh*32 + 8*t + 4*q2 .. +3], b64 store
                    *(uint2*)&my[n32 * LROW + mh * 32 + 8 * t + 4 * q2] = wv;
                }
            }

            // GEMM2: A2 frag = one ds_read_b128 of 8 consecutive bf16 hid values
            #pragma unroll
            for (int hl = 0; hl < 2; ++hl) {
                f32x4 d2 = {b2s, b2s, b2s, b2s};
                #pragma unroll
                for (int kc = 0; kc < 2; ++kc) {
                    F8 a2;
                    a2.q4 = *(const uint4*)((const unsigned char*)my
                              + (hl * 16 + n16) * (LROW * 2) + kc * 64 + q4 * 16);
                    d2 = __builtin_amdgcn_mfma_f32_16x16x32_bf16(a2.v, B2f[kc].v, d2, 0, 0, 0);
                }
                // D2: col = o = n16 (<8 real), rows = 4 consecutive pairs -> dwordx4
                if (n16 < NH) {
                    int p0 = pg + hl * 16 + q4 * 4;
                    int b = p0 >> 16, lo16 = p0 & 65535;
                    float4 st; st.x = d2[0]; st.y = d2[1]; st.z = d2[2]; st.w = d2[3];
                    *(float4*)(out + (size_t)b * (NH * 65536) + (size_t)n16 * 65536 + lo16) = st;
                }
            }
        }
    }
}

extern "C" void kernel_launch(void* const* d_in, const int* in_sizes, int n_in,
                              void* d_out, int out_size, void* d_ws, size_t ws_size,
                              hipStream_t stream) {
    const float* ff = (const float*)d_in[0];
    const float* W1 = (const float*)d_in[1];
    const float* b1 = (const float*)d_in[2];
    const float* W2 = (const float*)d_in[3];
    const float* b2 = (const float*)d_in[4];
    float* out = (float*)d_out;
    (void)d_ws; (void)ws_size;                  // workspace no longer used

    const int grid = NPAIRS / (128 * 4);        // 2048 blocks, 4 waves x 128 pairs
    relfeat_mfma4<<<grid, BLOCK, 0, stream>>>(ff, W1, b1, W2, b2, out);
}